// Round 10
// baseline (169.047 us; speedup 1.0000x reference)
//
#include <hip/hip_runtime.h>
#include <cstdint>
#include <cstddef>
#include <math.h>

typedef short bf16x8 __attribute__((ext_vector_type(8)));
typedef float f32x4 __attribute__((ext_vector_type(4)));
typedef unsigned long long u64;

#define NEG_HUGE (-3.0e38f)

__device__ __forceinline__ ushort f2bf(float x) {
    union { float f; uint32_t u; } a; a.f = x;
    uint32_t r = a.u + 0x7FFF + ((a.u >> 16) & 1);   // RNE
    return (ushort)(r >> 16);
}

__device__ __forceinline__ void gload_lds16(const void* g, void* l) {
    __builtin_amdgcn_global_load_lds(
        (const __attribute__((address_space(1))) uint32_t*)g,
        (__attribute__((address_space(3))) uint32_t*)l, 16, 0, 0);
}

#define VMCNT0() asm volatile("s_waitcnt vmcnt(0)" ::: "memory")
#define SBAR() do { __builtin_amdgcn_sched_barrier(0); \
    __builtin_amdgcn_s_barrier(); \
    __builtin_amdgcn_sched_barrier(0); } while (0)

// ---------------- weight prep ----------------
__global__ void prep_conv_T(const float* __restrict__ w, ushort* __restrict__ WT,
                            int Cin, int Cout, int Nrows, int Kpad) {
    int idx = blockIdx.x * 256 + threadIdx.x;
    if (idx >= Nrows * Kpad) return;
    int n = idx / Kpad, k = idx - n * Kpad;
    float val = 0.f;
    if (k < Cin * 3) {
        int co = n / 3, l = n % 3, ci = k / 3, lx = k % 3;
        int t = lx - l + 1;
        if (t >= 0 && t < 3) val = w[(co * Cin + ci) * 3 + t];
    }
    WT[idx] = f2bf(val);
}

__global__ void prep_lin_T(const float* __restrict__ wl, ushort* __restrict__ WT,
                           int K, int Nreal, int Npad) {
    int idx = blockIdx.x * 256 + threadIdx.x;
    if (idx >= Npad * K) return;
    int n = idx / K, k = idx - n * K;
    WT[idx] = (n < Nreal) ? f2bf(wl[n * K + k]) : (ushort)0;
}

// ---------------- pass 0: zero mask ----------------
__global__ void zero_mask(uint32_t* __restrict__ maskg) {
    int i = blockIdx.x * 256 + threadIdx.x;
    if (i < 16384 * 25) maskg[i] = 0;
}

// ---------------- pass 1: state fp32 -> bf16 [16384][2432] + visited bits ----------------
__global__ void convert_kernel(const float* __restrict__ state, ushort* __restrict__ Abf,
                               uint32_t* __restrict__ maskg) {
    int gid = blockIdx.x * 256 + threadIdx.x;
    if (gid >= 16384 * 304) return;
    int row = gid / 304, t = gid - row * 304;
    ushort* dst = Abf + (size_t)row * 2432 + t * 8;
    if (t >= 300) {                     // zero-pad cols 2400..2431
        *(uint4*)dst = (uint4){0, 0, 0, 0};
        return;
    }
    const float* src = state + (size_t)row * 2400 + t * 8;
    float4 a = *(const float4*)src, b = *(const float4*)(src + 4);
    float fv[8] = {a.x, a.y, a.z, a.w, b.x, b.y, b.z, b.w};
    ushort4 h0 = {f2bf(fv[0]), f2bf(fv[1]), f2bf(fv[2]), f2bf(fv[3])};
    ushort4 h1 = {f2bf(fv[4]), f2bf(fv[5]), f2bf(fv[6]), f2bf(fv[7])};
    *(ushort4*)dst = h0;
    *(ushort4*)(dst + 4) = h1;
    // visited-status slots: k%3==2 among k=t*8+j
    int k0 = t * 8;
    int j0 = (2 - (k0 % 3) + 3) % 3;
    #pragma unroll
    for (int j = 0; j < 8; ++j) {
        if (((j - j0) % 3) == 0 && j >= j0) {
            if (fv[j] != 0.0f) {
                int aidx = (k0 + j) / 3;
                atomicOr(&maskg[row * 25 + (aidx >> 5)], 1u << (aidx & 31));
            }
        }
    }
}

// ---------------- pass 2: finalize mask: visited | user_any | chan_full ----------------
__global__ void mask_finalize(uint32_t* __restrict__ maskg) {
    int row = blockIdx.x * 256 + threadIdx.x;
    if (row >= 16384) return;
    uint32_t* mw = maskg + (size_t)row * 25;
    uint32_t w[25];
    #pragma unroll
    for (int i = 0; i < 25; ++i) w[i] = mw[i];
    const u64 M40 = (1ull << 40) - 1;
    u64 ua = 0; uint32_t cf = 0;
    #pragma unroll
    for (int g = 0; g < 5; ++g) {
        uint32_t w0 = w[5*g], w1 = w[5*g+1], w2 = w[5*g+2], w3 = w[5*g+3], w4 = w[5*g+4];
        u64 c0 = ( (u64)w0        | ((u64)w1 << 32)) & M40;
        u64 c1 = (((u64)w1 >> 8)  | ((u64)w2 << 24)) & M40;
        u64 c2 = (((u64)w2 >> 16) | ((u64)w3 << 16)) & M40;
        u64 c3 = (((u64)w3 >> 24) | ((u64)w4 << 8))  & M40;
        ua |= c0 | c1 | c2 | c3;
        if (__popcll(c0) >= 2) cf |= 1u << (4*g);
        if (__popcll(c1) >= 2) cf |= 1u << (4*g+1);
        if (__popcll(c2) >= 2) cf |= 1u << (4*g+2);
        if (__popcll(c3) >= 2) cf |= 1u << (4*g+3);
    }
    #pragma unroll
    for (int g = 0; g < 5; ++g) {
        uint32_t w0 = w[5*g], w1 = w[5*g+1], w2 = w[5*g+2], w3 = w[5*g+3], w4 = w[5*g+4];
        u64 c0 = ( (u64)w0        | ((u64)w1 << 32)) & M40;
        u64 c1 = (((u64)w1 >> 8)  | ((u64)w2 << 24)) & M40;
        u64 c2 = (((u64)w2 >> 16) | ((u64)w3 << 16)) & M40;
        u64 c3 = (((u64)w3 >> 24) | ((u64)w4 << 8))  & M40;
        u64 m0v = c0 | ua | (((cf >> (4*g))     & 1u) ? M40 : 0ull);
        u64 m1v = c1 | ua | (((cf >> (4*g + 1)) & 1u) ? M40 : 0ull);
        u64 m2v = c2 | ua | (((cf >> (4*g + 2)) & 1u) ? M40 : 0ull);
        u64 m3v = c3 | ua | (((cf >> (4*g + 3)) & 1u) ? M40 : 0ull);
        mw[5*g]   = (uint32_t)m0v;
        mw[5*g+1] = (uint32_t)(m0v >> 32) | (uint32_t)(m1v << 8);
        mw[5*g+2] = (uint32_t)(m1v >> 24) | (uint32_t)(m2v << 16);
        mw[5*g+3] = (uint32_t)(m2v >> 16) | (uint32_t)(m3v << 24);
        mw[5*g+4] = (uint32_t)(m3v >> 8);
    }
}

// ---------------- uniform pipelined GEMM layer ----------------
// A[16384][K] bf16 (k-contig), WT[Ntot][K] bf16. Tile: MT=WM*MF*16 rows x NT=WN*NF*16 cols.
// Both A and W staged per 64-k chunk via global_load_lds, double-buffered.
// NOTE: no pointer-arrays into LDS (gfx950 static-initializer addrspacecast bug) —
// buffer bases computed as lds + b*size arithmetic.
template<int K, int MF, int NF, int WM, int WN, bool BDIV3, bool RELU, bool F32OUT>
__global__ __launch_bounds__(512, 4)
void glayer2(const ushort* __restrict__ Ag, const ushort* __restrict__ WTg,
             const float* __restrict__ bias, void* __restrict__ Yg, int ldy,
             const uint32_t* __restrict__ maskg)
{
    constexpr int MT = WM * MF * 16;
    constexpr int NT = WN * NF * 16;
    constexpr int NC = K / 64;
    constexpr int ABYTES = MT * 128;
    constexpr int WBYTES = NT * 128;
    constexpr int WSLOTS = NT * 8;
    extern __shared__ char lds[];
    // layout: [Ab0][Ab1][Wb0][Wb1]

    const int tid = threadIdx.x, lane = tid & 63, wid = tid >> 6;
    const int m0 = blockIdx.x * MT;
    const int n0 = blockIdx.y * NT;
    const int ml = lane & 15, kq = lane >> 4;
    const int mw = wid / WN, nw = wid % WN;
    const int mbase = mw * MF * 16;
    const int wn0 = nw * NF * 16;

    f32x4 acc[NF][MF];
    #pragma unroll
    for (int f = 0; f < NF; ++f)
        #pragma unroll
        for (int mi = 0; mi < MF; ++mi) acc[f][mi] = (f32x4){0.f, 0.f, 0.f, 0.f};

    auto stage = [&](int c, int b) {
        char* Ab = lds + b * ABYTES;
        char* Wb = lds + 2 * ABYTES + b * WBYTES;
        {   // A: MT*8 slots == 512
            int r = tid >> 3, o8 = tid & 7;
            gload_lds16(Ag + (size_t)(m0 + r) * K + c * 64 + ((o8 ^ (r & 7)) * 8),
                        Ab + tid * 16);
        }
        #pragma unroll
        for (int i = 0; i < (WSLOTS + 511) / 512; ++i) {
            int s = i * 512 + tid;
            if ((WSLOTS % 512 == 0) || s < WSLOTS) {
                int r = s >> 3, o8 = s & 7;
                gload_lds16(WTg + (size_t)(n0 + r) * K + c * 64 + ((o8 ^ (r & 7)) * 8),
                            Wb + s * 16);
            }
        }
    };
    auto mfmaC = [&](int b) {
        const char* Ab = lds + b * ABYTES;
        const char* Wb = lds + 2 * ABYTES + b * WBYTES;
        #pragma unroll
        for (int ks = 0; ks < 2; ++ks) {
            bf16x8 af[NF], bv[MF];
            #pragma unroll
            for (int f = 0; f < NF; ++f) {
                int n = wn0 + f * 16 + ml;
                af[f] = *(const bf16x8*)(Wb + n * 128 + (((ks * 4 + kq) * 16) ^ ((n & 7) << 4)));
            }
            #pragma unroll
            for (int mi = 0; mi < MF; ++mi) {
                int m = mbase + mi * 16 + ml;
                bv[mi] = *(const bf16x8*)(Ab + m * 128 + (((ks * 4 + kq) * 16) ^ ((m & 7) << 4)));
            }
            #pragma unroll
            for (int f = 0; f < NF; ++f)
                #pragma unroll
                for (int mi = 0; mi < MF; ++mi)
                    acc[f][mi] = __builtin_amdgcn_mfma_f32_16x16x32_bf16(af[f], bv[mi], acc[f][mi], 0, 0, 0);
        }
    };

    stage(0, 0);
    VMCNT0();
    SBAR();

    #pragma unroll 1
    for (int c = 0; c < NC; ++c) {
        if (c + 1 < NC) stage(c + 1, (c + 1) & 1);   // buffer (c+1)&1: all waves past
        mfmaC(c & 1);                                 //   barrier => done reading it
        if (c + 1 < NC) { VMCNT0(); SBAR(); }
    }

    // epilogue: D col(lane&15)=sample m, row((lane>>4)*4+r)=weight n
    const int nq4 = (lane >> 4) * 4;
    if (!F32OUT) {
        ushort* Y = (ushort*)Yg;
        #pragma unroll
        for (int f = 0; f < NF; ++f) {
            int n4 = n0 + wn0 + f * 16 + nq4;
            float bv0 = bias[BDIV3 ? n4 / 3 : n4];
            float bv1 = bias[BDIV3 ? (n4 + 1) / 3 : n4 + 1];
            float bv2 = bias[BDIV3 ? (n4 + 2) / 3 : n4 + 2];
            float bv3 = bias[BDIV3 ? (n4 + 3) / 3 : n4 + 3];
            #pragma unroll
            for (int mi = 0; mi < MF; ++mi) {
                int m = mbase + mi * 16 + ml;
                float x0 = acc[f][mi][0] + bv0, x1 = acc[f][mi][1] + bv1;
                float x2 = acc[f][mi][2] + bv2, x3 = acc[f][mi][3] + bv3;
                if (RELU) { x0 = fmaxf(x0, 0.f); x1 = fmaxf(x1, 0.f);
                            x2 = fmaxf(x2, 0.f); x3 = fmaxf(x3, 0.f); }
                ushort4 o = {f2bf(x0), f2bf(x1), f2bf(x2), f2bf(x3)};
                *(ushort4*)(Y + (size_t)(m0 + m) * ldy + n4) = o;
            }
        }
    } else {
        float* Y = (float*)Yg;
        #pragma unroll
        for (int f = 0; f < NF; ++f) {
            int nf = n0 + wn0 + f * 16;
            if (nf < 800) {
                int n4 = nf + nq4, sh = n4 & 31;
                float bv0 = bias[n4], bv1 = bias[n4 + 1];
                float bv2 = bias[n4 + 2], bv3 = bias[n4 + 3];
                #pragma unroll
                for (int mi = 0; mi < MF; ++mi) {
                    int m = mbase + mi * 16 + ml;
                    uint32_t mwv = maskg[(size_t)(m0 + m) * 25 + (nf >> 5)];
                    float4 v;
                    v.x = ((mwv >> (sh + 0)) & 1u) ? NEG_HUGE : (acc[f][mi][0] + bv0);
                    v.y = ((mwv >> (sh + 1)) & 1u) ? NEG_HUGE : (acc[f][mi][1] + bv1);
                    v.z = ((mwv >> (sh + 2)) & 1u) ? NEG_HUGE : (acc[f][mi][2] + bv2);
                    v.w = ((mwv >> (sh + 3)) & 1u) ? NEG_HUGE : (acc[f][mi][3] + bv3);
                    *(float4*)(Y + (size_t)(m0 + m) * ldy + n4) = v;
                }
            }
        }
    }
}

__global__ void ws_fail_kernel(float* out) {
    if (threadIdx.x == 0 && blockIdx.x == 0) out[0] = NAN;
}

extern "C" void kernel_launch(void* const* d_in, const int* in_sizes, int n_in,
                              void* d_out, int out_size, void* d_ws, size_t ws_size,
                              hipStream_t stream) {
    const float* state = (const float*)d_in[0];
    const float* w1  = (const float*)d_in[1];
    const float* b1  = (const float*)d_in[2];
    const float* w2  = (const float*)d_in[3];
    const float* b2  = (const float*)d_in[4];
    const float* w3  = (const float*)d_in[5];
    const float* b3  = (const float*)d_in[6];
    const float* wl1 = (const float*)d_in[7];
    const float* bl1 = (const float*)d_in[8];
    const float* wl2 = (const float*)d_in[9];
    const float* bl2 = (const float*)d_in[10];
    float* out = (float*)d_out;

    char* ws = (char*)d_ws;
    size_t off = 0;
    auto carve = [&](size_t bytes) {
        char* p = ws + off;
        off = (off + bytes + 255) & ~(size_t)255;
        return p;
    };
    ushort* W1T  = (ushort*)carve(384ull * 2432 * 2);
    ushort* W2T  = (ushort*)carve(768ull * 384 * 2);
    ushort* W3T  = (ushort*)carve(384ull * 768 * 2);
    ushort* WL1T = (ushort*)carve(192ull * 384 * 2);
    ushort* WL2T = (ushort*)carve(896ull * 192 * 2);
    ushort* Abf  = (ushort*)carve(16384ull * 2432 * 2);   // 79.7 MB
    ushort* X1g  = (ushort*)carve(16384ull * 384 * 2);    // 12.6 MB
    uint32_t* maskg = (uint32_t*)carve(16384ull * 25 * 4);
    // alias later intermediates into Abf (dead after conv1):
    ushort* X2g = Abf;                                     // 25.2 MB
    ushort* X3g = (ushort*)((char*)Abf + (32ull << 20));   // 12.6 MB
    ushort* X4g = (ushort*)((char*)Abf + (48ull << 20));   // 6.3 MB

    if (off > ws_size) {
        ws_fail_kernel<<<1, 64, 0, stream>>>(out);
        return;
    }

    prep_conv_T<<<(384 * 2432 + 255) / 256, 256, 0, stream>>>(w1, W1T, 800, 128, 384, 2432);
    prep_conv_T<<<(768 * 384 + 255) / 256, 256, 0, stream>>>(w2, W2T, 128, 256, 768, 384);
    prep_conv_T<<<(384 * 768 + 255) / 256, 256, 0, stream>>>(w3, W3T, 256, 128, 384, 768);
    prep_lin_T<<<(192 * 384 + 255) / 256, 256, 0, stream>>>(wl1, WL1T, 384, 192, 192);
    prep_lin_T<<<(896 * 192 + 255) / 256, 256, 0, stream>>>(wl2, WL2T, 192, 800, 896);

    zero_mask<<<(16384 * 25 + 255) / 256, 256, 0, stream>>>(maskg);
    convert_kernel<<<(16384 * 304 + 255) / 256, 256, 0, stream>>>(state, Abf, maskg);
    mask_finalize<<<16384 / 256, 256, 0, stream>>>(maskg);

    // conv1: Abf[16384,2432] @ W1T[384,2432] -> X1g
    auto kc1 = glayer2<2432, 2, 3, 2, 4, true, true, false>;
    (void)hipFuncSetAttribute(reinterpret_cast<const void*>(kc1),
                        hipFuncAttributeMaxDynamicSharedMemorySize, 65536);
    kc1<<<dim3(256, 2), 512, 65536, stream>>>(Abf, W1T, b1, X1g, 384, nullptr);

    // conv2: X1g[16384,384] @ W2T[768,384] -> X2g
    auto kc2 = glayer2<384, 2, 3, 2, 4, true, true, false>;
    (void)hipFuncSetAttribute(reinterpret_cast<const void*>(kc2),
                        hipFuncAttributeMaxDynamicSharedMemorySize, 65536);
    kc2<<<dim3(256, 4), 512, 65536, stream>>>(X1g, W2T, b2, X2g, 768, nullptr);

    // conv3: X2g[16384,768] @ W3T[384,768] -> X3g
    auto kc3 = glayer2<768, 2, 3, 2, 4, true, true, false>;
    (void)hipFuncSetAttribute(reinterpret_cast<const void*>(kc3),
                        hipFuncAttributeMaxDynamicSharedMemorySize, 65536);
    kc3<<<dim3(256, 2), 512, 65536, stream>>>(X2g, W3T, b3, X3g, 384, nullptr);

    // lin1: X3g[16384,384] @ WL1T[192,384] -> X4g
    auto kc4 = glayer2<384, 2, 3, 2, 4, false, true, false>;
    (void)hipFuncSetAttribute(reinterpret_cast<const void*>(kc4),
                        hipFuncAttributeMaxDynamicSharedMemorySize, 65536);
    kc4<<<dim3(256, 1), 512, 65536, stream>>>(X3g, WL1T, bl1, X4g, 192, nullptr);

    // lin2 + mask: X4g[16384,192] @ WL2T[896,192] -> out[16384,800] f32
    auto kc5 = glayer2<192, 1, 7, 4, 2, false, false, true>;
    (void)hipFuncSetAttribute(reinterpret_cast<const void*>(kc5),
                        hipFuncAttributeMaxDynamicSharedMemorySize, 73728);
    kc5<<<dim3(256, 4), 512, 73728, stream>>>(X4g, WL2T, bl2, out, 800, maskg);
}